// Round 7
// baseline (176.765 us; speedup 1.0000x reference)
//
#include <hip/hip_runtime.h>
#include <stdint.h>

// Problem dims (fixed)
#define BB 2
#define SS 2048
#define DD 1024
#define NH 16
#define HD 64
#define MM 4096   // BB*SS

typedef __bf16 bf16x8 __attribute__((ext_vector_type(8)));
typedef __bf16 bf16x4 __attribute__((ext_vector_type(4)));
typedef float  f32x4  __attribute__((ext_vector_type(4)));

__device__ __forceinline__ unsigned short f2bf(float f) {
    __bf16 h = (__bf16)f;                       // hw v_cvt, RNE
    return __builtin_bit_cast(unsigned short, h);
}

// async global->LDS, 16B per lane. LDS dst must be wave-uniform base + lane*16.
// NOTE (R5 lesson): this is also the coalescing transform — global side must be
// lane-contiguous. Direct global->VGPR fragment loads (2KB lane stride) ran 2.3x
// slower from transaction explosion despite zero barriers.
// NOTE (R6 lesson): 2-wave blocks give the SAME waves/CU as 4-wave at half grid;
// they only double per-wave staging overhead. Keep 256-thread attn blocks.
__device__ __forceinline__ void async_cp16(const void* g, const void* l) {
    __builtin_amdgcn_global_load_lds(
        (const __attribute__((address_space(1))) void*)(uintptr_t)g,
        (__attribute__((address_space(3))) void*)(uint32_t)(uintptr_t)l,
        16, 0, 0);
}

__device__ __forceinline__ f32x4 mfma16(bf16x8 a, bf16x8 b, f32x4 c) {
    return __builtin_amdgcn_mfma_f32_16x16x32_bf16(a, b, c, 0, 0, 0);
}

// ---------------- fused prep: H->Hb+Vt (blocks 0..511) and W->bf16 (blocks 512..2047) ----
__global__ __launch_bounds__(256) void k_prep(const float* __restrict__ H,
                                              const float* __restrict__ Wq,
                                              const float* __restrict__ Wk,
                                              const float* __restrict__ Wo,
                                              unsigned short* __restrict__ Hb,
                                              unsigned short* __restrict__ Vt,
                                              unsigned short* __restrict__ Wqb,
                                              unsigned short* __restrict__ Wkb,
                                              unsigned short* __restrict__ Wob) {
    __shared__ float tile[128][68];
    const int bx = blockIdx.x;
    const int t = threadIdx.x;
    if (bx >= 512) {  // weight conversion
        int g = bx - 512;
        const float* src; unsigned short* dst; int base;
        if (g < 512)       { src = Wq; dst = Wqb; base = g; }
        else if (g < 1024) { src = Wk; dst = Wkb; base = g - 512; }
        else               { src = Wo; dst = Wob; base = g - 1024; }
        int i = (base * 256 + t) * 8;
        float4 a = *(const float4*)(src + i);
        float4 b = *(const float4*)(src + i + 4);
        unsigned short o[8];
        o[0] = f2bf(a.x); o[1] = f2bf(a.y); o[2] = f2bf(a.z); o[3] = f2bf(a.w);
        o[4] = f2bf(b.x); o[5] = f2bf(b.y); o[6] = f2bf(b.z); o[7] = f2bf(b.w);
        *(ulonglong2*)(dst + i) = *(ulonglong2*)o;
        return;
    }
    const int sb = bx & 15, h = (bx >> 4) & 15, b = bx >> 8;
    const int col4 = t & 15;
    const int srow0 = t >> 4;
#pragma unroll
    for (int p = 0; p < 8; ++p) {
        int s = p * 16 + srow0;
        float4 v = *(const float4*)(H + (size_t)(b * SS + sb * 128 + s) * DD + h * HD + col4 * 4);
        *(float4*)&tile[s][col4 * 4] = v;
    }
    __syncthreads();
#pragma unroll
    for (int it = 0; it < 4; ++it) {
        int task = it * 256 + t;
        int s = task >> 3;
        int dg = task & 7;
        unsigned short pk[8];
#pragma unroll
        for (int j = 0; j < 8; ++j) pk[j] = f2bf(tile[s][dg * 8 + j]);
        *(ulonglong2*)(Hb + (size_t)(b * SS + sb * 128 + s) * DD + h * HD + dg * 8) = *(ulonglong2*)pk;
    }
#pragma unroll
    for (int it = 0; it < 4; ++it) {
        int task = it * 256 + t;
        int d = task >> 4;
        int sg = task & 15;
        unsigned short pk[8];
#pragma unroll
        for (int j = 0; j < 8; ++j) pk[j] = f2bf(tile[sg * 8 + j][d]);
        *(ulonglong2*)(Vt + (size_t)((b * NH + h) * HD + d) * SS + sb * 128 + sg * 8) = *(ulonglong2*)pk;
    }
}

// ---------------- TM x 128 MFMA GEMM, BK=64, double-buffered, 1 barrier/iter ----------------
template <int TM, bool BF16OUT>
__device__ __forceinline__ void gemm_body(const unsigned short* __restrict__ A,
                                          const unsigned short* __restrict__ Bt,
                                          const float* __restrict__ bias,
                                          void* __restrict__ Cp, float oscale) {
    constexpr int MT = TM / 32;
    constexpr int AR = TM / 32;
    __shared__ unsigned short lsA[2][TM * 64];
    __shared__ unsigned short lsB[2][128 * 64];
    const int tid = threadIdx.x;
    const int lane = tid & 63;
    const int w = tid >> 6;
    const int wm = w & 1, wn = w >> 1;
    const int r = lane & 15, quad = lane >> 4;
    const int mBase = blockIdx.y * TM;
    const int nBase = blockIdx.x * 128;

    const unsigned short* gA[AR]; uint laOff[AR];
#pragma unroll
    for (int t = 0; t < AR; ++t) {
        int l = t * 256 + tid;
        int c = l ^ ((l >> 3) & 7);
        int row = c >> 3, kc = c & 7;
        gA[t] = A + (size_t)(mBase + row) * 1024 + kc * 8;
        laOff[t] = l * 8;
    }
    const unsigned short* gB[4]; uint lbOff[4];
#pragma unroll
    for (int t = 0; t < 4; ++t) {
        int l = t * 256 + tid;
        int c = l ^ ((l >> 3) & 7);
        int row = c >> 3, kc = c & 7;
        gB[t] = Bt + (size_t)(nBase + row) * 1024 + kc * 8;
        lbOff[t] = l * 8;
    }
    uint aOff[2][MT], bOff[2][4];
#pragma unroll
    for (int hh = 0; hh < 2; ++hh) {
#pragma unroll
        for (int mt = 0; mt < MT; ++mt) {
            int rowA = wm * (TM / 2) + mt * 16 + r;
            int c = rowA * 8 + hh * 4 + quad;
            aOff[hh][mt] = (uint)((c ^ ((c >> 3) & 7)) * 8);
        }
#pragma unroll
        for (int nt = 0; nt < 4; ++nt) {
            int rowB = wn * 64 + nt * 16 + r;
            int c = rowB * 8 + hh * 4 + quad;
            bOff[hh][nt] = (uint)((c ^ ((c >> 3) & 7)) * 8);
        }
    }

    f32x4 acc[MT][4];
#pragma unroll
    for (int i = 0; i < MT; ++i)
#pragma unroll
        for (int j = 0; j < 4; ++j) acc[i][j] = f32x4{0.f, 0.f, 0.f, 0.f};

    auto stage = [&](int buf) {
#pragma unroll
        for (int t = 0; t < AR; ++t) { async_cp16(gA[t], &lsA[buf][laOff[t]]); gA[t] += 64; }
#pragma unroll
        for (int t = 0; t < 4; ++t)  { async_cp16(gB[t], &lsB[buf][lbOff[t]]); gB[t] += 64; }
    };

    stage(0);
    for (int kb = 0; kb < 16; ++kb) {
        const int cur = kb & 1;
        __syncthreads();
        if (kb + 1 < 16) stage(cur ^ 1);

#pragma unroll
        for (int hh = 0; hh < 2; ++hh) {
            bf16x8 af[MT], bf[4];
#pragma unroll
            for (int mt = 0; mt < MT; ++mt) af[mt] = *(const bf16x8*)&lsA[cur][aOff[hh][mt]];
#pragma unroll
            for (int nt = 0; nt < 4; ++nt)  bf[nt] = *(const bf16x8*)&lsB[cur][bOff[hh][nt]];
#pragma unroll
            for (int mt = 0; mt < MT; ++mt)
#pragma unroll
                for (int nt = 0; nt < 4; ++nt)
                    acc[mt][nt] = mfma16(af[mt], bf[nt], acc[mt][nt]);
        }
    }

    float bv[4];
#pragma unroll
    for (int nt = 0; nt < 4; ++nt) bv[nt] = bias[nBase + wn * 64 + nt * 16 + r];
#pragma unroll
    for (int mt = 0; mt < MT; ++mt)
#pragma unroll
        for (int nt = 0; nt < 4; ++nt) {
            int colg = nBase + wn * 64 + nt * 16 + r;
#pragma unroll
            for (int reg = 0; reg < 4; ++reg) {
                int rowg = mBase + wm * (TM / 2) + mt * 16 + quad * 4 + reg;
                float v = (acc[mt][nt][reg] + bv[nt]) * oscale;
                if (BF16OUT)
                    ((unsigned short*)Cp)[(size_t)rowg * 1024 + colg] = f2bf(v);
                else
                    ((float*)Cp)[(size_t)rowg * 1024 + colg] = v;
            }
        }
}

#define QSCALE 0.1803368801111137f   // (1/sqrt(64)) * log2(e)

__global__ __launch_bounds__(256) void k_gemm_qk(const unsigned short* __restrict__ Hb,
                                                 const unsigned short* __restrict__ Wqb,
                                                 const unsigned short* __restrict__ Wkb,
                                                 const float* __restrict__ bq,
                                                 const float* __restrict__ bk,
                                                 unsigned short* __restrict__ Q,
                                                 unsigned short* __restrict__ K) {
    const unsigned short* Bt = blockIdx.z ? Wkb : Wqb;
    const float* bias = blockIdx.z ? bk : bq;
    unsigned short* C = blockIdx.z ? K : Q;
    float os = blockIdx.z ? 1.0f : QSCALE;
    gemm_body<128, true>(Hb, Bt, bias, C, os);
}

__global__ __launch_bounds__(256) void k_gemm_out(const unsigned short* __restrict__ Ctx,
                                                  const unsigned short* __restrict__ Wob,
                                                  const float* __restrict__ bo,
                                                  float* __restrict__ Out) {
    gemm_body<64, false>(Ctx, Wob, bo, Out, 1.0f);
}

// ---------------- flash attention: KT=128 k-tiles (16 barriers), XCD-swizzled grid ----------
// 512 blocks x 256 threads; wave owns 32 q-rows (2 subtiles sharing K/V frags).
// LDS 80KB = 2 blocks/CU (grid-limited anyway). Per iter: stage 128 kpos of K+V,
// one barrier, two 64-k compute halves. Blocks sharing a head's K/V map to one XCD
// (id&7 constant per (h,b)) for L2 locality. Q pre-scaled by scale*log2e.
__global__ __launch_bounds__(256) void k_attn(const unsigned short* __restrict__ Q,
                                              const unsigned short* __restrict__ K,
                                              const unsigned short* __restrict__ Vt,
                                              unsigned short* __restrict__ Ctx) {
    __shared__ unsigned short lsK[2][128 * 64];  // [buf][half*64 + sigma-row][d]
    __shared__ unsigned short lsV[2][128 * 64];  // [buf][half*64*64 + d*64 + kpos]
    __shared__ unsigned short lsP[4 * 2048];     // per-wave [q32][k64]
    const int tid = threadIdx.x;
    const int lane = tid & 63;
    const int w = tid >> 6;
    const int r = lane & 15, quad = lane >> 4;
    // XCD swizzle: all 16 q-blocks of one (h,b) share id&7 -> same XCD L2
    const int id = blockIdx.x;
    const int xcd = id & 7, j = id >> 3;
    const int hb = xcd + 8 * (j & 3);
    const int qb = j >> 2;
    const int h = hb & 15, b = hb >> 4;

    // Q A-fragments: A[m=lane&15][k=quad*8+j (+32t)]
    bf16x8 aq[2][2];
#pragma unroll
    for (int sub = 0; sub < 2; ++sub) {
        const int qrow = qb * 128 + w * 32 + sub * 16 + r;
        const size_t qoff = (size_t)(b * SS + qrow) * DD + h * HD;
        aq[sub][0] = *(const bf16x8*)(Q + qoff + quad * 8);
        aq[sub][1] = *(const bf16x8*)(Q + qoff + 32 + quad * 8);
    }

    f32x4 accO[2][4];
#pragma unroll
    for (int sub = 0; sub < 2; ++sub)
#pragma unroll
        for (int nt = 0; nt < 4; ++nt) accO[sub][nt] = f32x4{0.f, 0.f, 0.f, 0.f};
    float lsum[2][4] = {{0.f, 0.f, 0.f, 0.f}, {0.f, 0.f, 0.f, 0.f}};

    // staging addresses: 4 rounds K + 4 rounds V cover 128 rows x 8 chunks each.
    // chunk index l swizzled (bits 0-2 ^= bits 3-5); half = bit 9 preserved.
    const unsigned short* gK[4]; const unsigned short* gV[4]; uint lO[4];
#pragma unroll
    for (int t = 0; t < 4; ++t) {
        int l = t * 256 + tid;
        int c = l ^ ((l >> 3) & 7);
        int half = c >> 9, kc = c & 7;
        int rr = (c >> 3) & 63;
        int srow = half * 64 + 4 * (rr & 15) + (rr >> 4);   // sigma within 64-half
        gK[t] = K + (size_t)(b * SS + srow) * DD + h * HD + kc * 8;
        gV[t] = Vt + (size_t)((b * NH + h) * HD + rr) * SS + half * 64 + kc * 8;
        lO[t] = l * 8;
    }
    // LDS frag offsets within a 64-half (add half*4096 shorts; swizzle commutes)
    uint off[2][4];
#pragma unroll
    for (int t = 0; t < 2; ++t)
#pragma unroll
        for (int nt = 0; nt < 4; ++nt) {
            int rowX = nt * 16 + r;
            int c = rowX * 8 + t * 4 + quad;
            off[t][nt] = (uint)((c ^ ((c >> 3) & 7)) * 8);
        }
    // P write/read offsets (row stride 64 shorts, 16B-chunk xor-swizzle by row&7)
    uint pw[4], pr[2];
#pragma unroll
    for (int reg = 0; reg < 4; ++reg) {
        int prow = quad * 4 + reg;
        pw[reg] = (uint)(prow * 64 + ((r >> 1) ^ (prow & 7)) * 8 + (r & 1) * 4);
    }
#pragma unroll
    for (int t = 0; t < 2; ++t)
        pr[t] = (uint)(r * 64 + ((4 * t + quad) ^ (r & 7)) * 8);
    unsigned short* Pw = lsP + w * 2048;

    auto stage = [&](int buf) {
#pragma unroll
        for (int t = 0; t < 4; ++t) {
            async_cp16(gK[t], &lsK[buf][lO[t]]); gK[t] += 128 * DD;
            async_cp16(gV[t], &lsV[buf][lO[t]]); gV[t] += 128;
        }
    };

    stage(0);
    for (int kt = 0; kt < 16; ++kt) {
        const int cur = kt & 1;
        __syncthreads();   // drains vmcnt: buf[cur] ready, prev reads of buf[cur^1] done
        if (kt + 1 < 16) stage(cur ^ 1);

#pragma unroll
        for (int half = 0; half < 2; ++half) {
            const uint ho = (uint)half * 4096;

            // S = Q K^T, both subtiles share each K fragment
            f32x4 s[2][4];
#pragma unroll
            for (int sub = 0; sub < 2; ++sub)
#pragma unroll
                for (int nt = 0; nt < 4; ++nt) s[sub][nt] = f32x4{0.f, 0.f, 0.f, 0.f};
#pragma unroll
            for (int t = 0; t < 2; ++t)
#pragma unroll
                for (int nt = 0; nt < 4; ++nt) {
                    bf16x8 bk = *(const bf16x8*)&lsK[cur][ho + off[t][nt]];
                    s[0][nt] = mfma16(aq[0][t], bk, s[0][nt]);
                    s[1][nt] = mfma16(aq[1][t], bk, s[1][nt]);
                }

            // p = exp2(s); packed P write (cols = actual kpos 4r+nt within half)
#pragma unroll
            for (int sub = 0; sub < 2; ++sub)
#pragma unroll
                for (int reg = 0; reg < 4; ++reg) {
                    float p0 = __builtin_amdgcn_exp2f(s[sub][0][reg]);
                    float p1 = __builtin_amdgcn_exp2f(s[sub][1][reg]);
                    float p2 = __builtin_amdgcn_exp2f(s[sub][2][reg]);
                    float p3 = __builtin_amdgcn_exp2f(s[sub][3][reg]);
                    lsum[sub][reg] += (p0 + p1) + (p2 + p3);
                    bf16x4 pk = {(__bf16)p0, (__bf16)p1, (__bf16)p2, (__bf16)p3};
                    *(bf16x4*)&Pw[sub * 1024 + pw[reg]] = pk;
                }
            // no barrier: P is per-wave, same-wave DS ops are ordered

            // O += P V, both subtiles share each V fragment
#pragma unroll
            for (int t = 0; t < 2; ++t) {
                bf16x8 ap0 = *(const bf16x8*)&Pw[pr[t]];
                bf16x8 ap1 = *(const bf16x8*)&Pw[1024 + pr[t]];
#pragma unroll
                for (int nt = 0; nt < 4; ++nt) {
                    bf16x8 bv = *(const bf16x8*)&lsV[cur][ho + off[t][nt]];
                    accO[0][nt] = mfma16(ap0, bv, accO[0][nt]);
                    accO[1][nt] = mfma16(ap1, bv, accO[1][nt]);
                }
            }
        }
    }

    // epilogue: reduce l across the 16 row-lanes, then O/l -> Ctx bf16
#pragma unroll
    for (int sub = 0; sub < 2; ++sub) {
        float linv[4];
#pragma unroll
        for (int reg = 0; reg < 4; ++reg) {
            float l = lsum[sub][reg];
            l += __shfl_xor(l, 1);
            l += __shfl_xor(l, 2);
            l += __shfl_xor(l, 4);
            l += __shfl_xor(l, 8);
            linv[reg] = 1.0f / l;
        }
#pragma unroll
        for (int nt = 0; nt < 4; ++nt) {
            int d = nt * 16 + r;
#pragma unroll
            for (int reg = 0; reg < 4; ++reg) {
                int qr = qb * 128 + w * 32 + sub * 16 + quad * 4 + reg;
                Ctx[(size_t)(b * SS + qr) * DD + h * HD + d] = f2bf(accO[sub][nt][reg] * linv[reg]);
            }
        }
    }
}

extern "C" void kernel_launch(void* const* d_in, const int* in_sizes, int n_in,
                              void* d_out, int out_size, void* d_ws, size_t ws_size,
                              hipStream_t stream) {
    (void)in_sizes; (void)n_in; (void)out_size; (void)ws_size;
    const float* H  = (const float*)d_in[0];
    const float* Wq = (const float*)d_in[1];
    const float* bq = (const float*)d_in[2];
    const float* Wk = (const float*)d_in[3];
    const float* bk = (const float*)d_in[4];
    const float* Wo = (const float*)d_in[5];
    const float* bo = (const float*)d_in[6];
    float* Out = (float*)d_out;

    char* ws = (char*)d_ws;
    unsigned short* Hb  = (unsigned short*)(ws);                 // 8 MB
    unsigned short* Qb  = (unsigned short*)(ws + 8388608);       // 8 MB (pre-scaled)
    unsigned short* Kb  = (unsigned short*)(ws + 16777216);      // 8 MB
    unsigned short* Ctx = (unsigned short*)(ws + 25165824);      // 8 MB
    unsigned short* Vt  = (unsigned short*)(ws + 33554432);      // 8 MB
    unsigned short* Wqb = (unsigned short*)(ws + 41943040);      // 2 MB
    unsigned short* Wkb = (unsigned short*)(ws + 44040192);      // 2 MB
    unsigned short* Wob = (unsigned short*)(ws + 46137344);      // 2 MB

    k_prep<<<dim3(2048), dim3(256), 0, stream>>>(H, Wq, Wk, Wo, Hb, Vt, Wqb, Wkb, Wob);
    k_gemm_qk<<<dim3(8, 32, 2), dim3(256), 0, stream>>>(Hb, Wqb, Wkb, bq, bk, Qb, Kb);
    k_attn<<<dim3(512), dim3(256), 0, stream>>>(Qb, Kb, Vt, Ctx);
    k_gemm_out<<<dim3(8, 64, 1), dim3(256), 0, stream>>>(Ctx, Wob, bo, Out);
}

// Round 8
// 169.598 us; speedup vs baseline: 1.0423x; 1.0423x over previous
//
#include <hip/hip_runtime.h>
#include <stdint.h>

// Problem dims (fixed)
#define BB 2
#define SS 2048
#define DD 1024
#define NH 16
#define HD 64
#define MM 4096   // BB*SS

typedef __bf16 bf16x8 __attribute__((ext_vector_type(8)));
typedef __bf16 bf16x4 __attribute__((ext_vector_type(4)));
typedef float  f32x4  __attribute__((ext_vector_type(4)));

__device__ __forceinline__ unsigned short f2bf(float f) {
    __bf16 h = (__bf16)f;                       // hw v_cvt, RNE
    return __builtin_bit_cast(unsigned short, h);
}

// async global->LDS, 16B per lane. LDS dst must be wave-uniform base + lane*16.
// R5 lesson: this is also the coalescing transform (global side lane-contiguous).
// R6 lesson: 2-wave blocks = same waves/CU as 4-wave at half grid; keep 256 threads.
// R7 lesson: XCD swizzle cut FETCH 70->12MB but time flat -> attn is chain-latency-bound.
__device__ __forceinline__ void async_cp16(const void* g, const void* l) {
    __builtin_amdgcn_global_load_lds(
        (const __attribute__((address_space(1))) void*)(uintptr_t)g,
        (__attribute__((address_space(3))) void*)(uint32_t)(uintptr_t)l,
        16, 0, 0);
}

__device__ __forceinline__ f32x4 mfma16(bf16x8 a, bf16x8 b, f32x4 c) {
    return __builtin_amdgcn_mfma_f32_16x16x32_bf16(a, b, c, 0, 0, 0);
}

// ---------------- fused prep: H->Hb+Vt (blocks 0..511) and W->bf16 (blocks 512..2047) ----
__global__ __launch_bounds__(256) void k_prep(const float* __restrict__ H,
                                              const float* __restrict__ Wq,
                                              const float* __restrict__ Wk,
                                              const float* __restrict__ Wo,
                                              unsigned short* __restrict__ Hb,
                                              unsigned short* __restrict__ Vt,
                                              unsigned short* __restrict__ Wqb,
                                              unsigned short* __restrict__ Wkb,
                                              unsigned short* __restrict__ Wob) {
    __shared__ float tile[128][68];
    const int bx = blockIdx.x;
    const int t = threadIdx.x;
    if (bx >= 512) {  // weight conversion
        int g = bx - 512;
        const float* src; unsigned short* dst; int base;
        if (g < 512)       { src = Wq; dst = Wqb; base = g; }
        else if (g < 1024) { src = Wk; dst = Wkb; base = g - 512; }
        else               { src = Wo; dst = Wob; base = g - 1024; }
        int i = (base * 256 + t) * 8;
        float4 a = *(const float4*)(src + i);
        float4 b = *(const float4*)(src + i + 4);
        unsigned short o[8];
        o[0] = f2bf(a.x); o[1] = f2bf(a.y); o[2] = f2bf(a.z); o[3] = f2bf(a.w);
        o[4] = f2bf(b.x); o[5] = f2bf(b.y); o[6] = f2bf(b.z); o[7] = f2bf(b.w);
        *(ulonglong2*)(dst + i) = *(ulonglong2*)o;
        return;
    }
    const int sb = bx & 15, h = (bx >> 4) & 15, b = bx >> 8;
    const int col4 = t & 15;
    const int srow0 = t >> 4;
#pragma unroll
    for (int p = 0; p < 8; ++p) {
        int s = p * 16 + srow0;
        float4 v = *(const float4*)(H + (size_t)(b * SS + sb * 128 + s) * DD + h * HD + col4 * 4);
        *(float4*)&tile[s][col4 * 4] = v;
    }
    __syncthreads();
#pragma unroll
    for (int it = 0; it < 4; ++it) {
        int task = it * 256 + t;
        int s = task >> 3;
        int dg = task & 7;
        unsigned short pk[8];
#pragma unroll
        for (int j = 0; j < 8; ++j) pk[j] = f2bf(tile[s][dg * 8 + j]);
        *(ulonglong2*)(Hb + (size_t)(b * SS + sb * 128 + s) * DD + h * HD + dg * 8) = *(ulonglong2*)pk;
    }
#pragma unroll
    for (int it = 0; it < 4; ++it) {
        int task = it * 256 + t;
        int d = task >> 4;
        int sg = task & 15;
        unsigned short pk[8];
#pragma unroll
        for (int j = 0; j < 8; ++j) pk[j] = f2bf(tile[sg * 8 + j][d]);
        *(ulonglong2*)(Vt + (size_t)((b * NH + h) * HD + d) * SS + sb * 128 + sg * 8) = *(ulonglong2*)pk;
    }
}

// ---------------- TM x 128 MFMA GEMM, BK=64, double-buffered, 1 barrier/iter ----------------
template <int TM, bool BF16OUT>
__device__ __forceinline__ void gemm_body(const unsigned short* __restrict__ A,
                                          const unsigned short* __restrict__ Bt,
                                          const float* __restrict__ bias,
                                          void* __restrict__ Cp, float oscale,
                                          int mBase, int nBase) {
    constexpr int MT = TM / 32;
    constexpr int AR = TM / 32;
    __shared__ unsigned short lsA[2][TM * 64];
    __shared__ unsigned short lsB[2][128 * 64];
    const int tid = threadIdx.x;
    const int lane = tid & 63;
    const int w = tid >> 6;
    const int wm = w & 1, wn = w >> 1;
    const int r = lane & 15, quad = lane >> 4;

    const unsigned short* gA[AR]; uint laOff[AR];
#pragma unroll
    for (int t = 0; t < AR; ++t) {
        int l = t * 256 + tid;
        int c = l ^ ((l >> 3) & 7);
        int row = c >> 3, kc = c & 7;
        gA[t] = A + (size_t)(mBase + row) * 1024 + kc * 8;
        laOff[t] = l * 8;
    }
    const unsigned short* gB[4]; uint lbOff[4];
#pragma unroll
    for (int t = 0; t < 4; ++t) {
        int l = t * 256 + tid;
        int c = l ^ ((l >> 3) & 7);
        int row = c >> 3, kc = c & 7;
        gB[t] = Bt + (size_t)(nBase + row) * 1024 + kc * 8;
        lbOff[t] = l * 8;
    }
    uint aOff[2][MT], bOff[2][4];
#pragma unroll
    for (int hh = 0; hh < 2; ++hh) {
#pragma unroll
        for (int mt = 0; mt < MT; ++mt) {
            int rowA = wm * (TM / 2) + mt * 16 + r;
            int c = rowA * 8 + hh * 4 + quad;
            aOff[hh][mt] = (uint)((c ^ ((c >> 3) & 7)) * 8);
        }
#pragma unroll
        for (int nt = 0; nt < 4; ++nt) {
            int rowB = wn * 64 + nt * 16 + r;
            int c = rowB * 8 + hh * 4 + quad;
            bOff[hh][nt] = (uint)((c ^ ((c >> 3) & 7)) * 8);
        }
    }

    f32x4 acc[MT][4];
#pragma unroll
    for (int i = 0; i < MT; ++i)
#pragma unroll
        for (int j = 0; j < 4; ++j) acc[i][j] = f32x4{0.f, 0.f, 0.f, 0.f};

    auto stage = [&](int buf) {
#pragma unroll
        for (int t = 0; t < AR; ++t) { async_cp16(gA[t], &lsA[buf][laOff[t]]); gA[t] += 64; }
#pragma unroll
        for (int t = 0; t < 4; ++t)  { async_cp16(gB[t], &lsB[buf][lbOff[t]]); gB[t] += 64; }
    };

    stage(0);
    for (int kb = 0; kb < 16; ++kb) {
        const int cur = kb & 1;
        __syncthreads();
        if (kb + 1 < 16) stage(cur ^ 1);

#pragma unroll
        for (int hh = 0; hh < 2; ++hh) {
            bf16x8 af[MT], bf[4];
#pragma unroll
            for (int mt = 0; mt < MT; ++mt) af[mt] = *(const bf16x8*)&lsA[cur][aOff[hh][mt]];
#pragma unroll
            for (int nt = 0; nt < 4; ++nt)  bf[nt] = *(const bf16x8*)&lsB[cur][bOff[hh][nt]];
#pragma unroll
            for (int mt = 0; mt < MT; ++mt)
#pragma unroll
                for (int nt = 0; nt < 4; ++nt)
                    acc[mt][nt] = mfma16(af[mt], bf[nt], acc[mt][nt]);
        }
    }

    float bv[4];
#pragma unroll
    for (int nt = 0; nt < 4; ++nt) bv[nt] = bias[nBase + wn * 64 + nt * 16 + r];
#pragma unroll
    for (int mt = 0; mt < MT; ++mt)
#pragma unroll
        for (int nt = 0; nt < 4; ++nt) {
            int colg = nBase + wn * 64 + nt * 16 + r;
#pragma unroll
            for (int reg = 0; reg < 4; ++reg) {
                int rowg = mBase + wm * (TM / 2) + mt * 16 + quad * 4 + reg;
                float v = (acc[mt][nt][reg] + bv[nt]) * oscale;
                if (BF16OUT)
                    ((unsigned short*)Cp)[(size_t)rowg * 1024 + colg] = f2bf(v);
                else
                    ((float*)Cp)[(size_t)rowg * 1024 + colg] = v;
            }
        }
}

#define QSCALE 0.1803368801111137f   // (1/sqrt(64)) * log2(e)

// 512 blocks, id = x*64 + y' so all 8 n-blocks of one A-strip share id%8 -> one XCD L2.
__global__ __launch_bounds__(256) void k_gemm_qk(const unsigned short* __restrict__ Hb,
                                                 const unsigned short* __restrict__ Wqb,
                                                 const unsigned short* __restrict__ Wkb,
                                                 const float* __restrict__ bq,
                                                 const float* __restrict__ bk,
                                                 unsigned short* __restrict__ Q,
                                                 unsigned short* __restrict__ K) {
    const int id = blockIdx.x;
    const int x = id >> 6, yp = id & 63;
    const int z = yp >> 5, y = yp & 31;
    const unsigned short* Bt = z ? Wkb : Wqb;
    const float* bias = z ? bk : bq;
    unsigned short* C = z ? K : Q;
    float os = z ? 1.0f : QSCALE;
    gemm_body<128, true>(Hb, Bt, bias, C, os, y * 128, x * 128);
}

__global__ __launch_bounds__(256) void k_gemm_out(const unsigned short* __restrict__ Ctx,
                                                  const unsigned short* __restrict__ Wob,
                                                  const float* __restrict__ bo,
                                                  float* __restrict__ Out) {
    const int id = blockIdx.x;
    const int x = id >> 6, y = id & 63;
    gemm_body<64, false>(Ctx, Wob, bo, Out, 1.0f, y * 64, x * 128);
}

// ---------------- flash attention: PV software-pipelined one tile behind -----------------
// 512 blocks x 256 threads, wave owns 32 q-rows (2 subtiles). KT=64. Per iter:
// barrier; prefetch(i+1); QK(i); PV(i-1); exp(i)+Pwrite(i). The P LDS round-trip and
// the QK->exp MFMA latency now hide behind each other. K dbuf, V TRIPLE buf (PV(i-1)
// reads V[(i-1)%3] while prefetch writes V[(i+1)%3]), P per-wave dbuf. LDS 72KB ->
// 2 blocks/CU (grid-capped anyway). XCD-swizzled grid (R7: FETCH 70->12MB).
__global__ __launch_bounds__(256) void k_attn(const unsigned short* __restrict__ Q,
                                              const unsigned short* __restrict__ K,
                                              const unsigned short* __restrict__ Vt,
                                              unsigned short* __restrict__ Ctx) {
    __shared__ unsigned short lsK[2][64 * 64];   // [buf][sigma-row][d]
    __shared__ unsigned short lsV[3][64 * 64];   // [buf][d][kpos]
    __shared__ unsigned short lsP[4 * 2 * 2048]; // per-wave, 2 bufs of [q32][k64]
    const int tid = threadIdx.x;
    const int lane = tid & 63;
    const int w = tid >> 6;
    const int r = lane & 15, quad = lane >> 4;
    // XCD swizzle: all 16 q-blocks of one (h,b) share id&7 -> same XCD L2
    const int id = blockIdx.x;
    const int xcd = id & 7, j = id >> 3;
    const int hb = xcd + 8 * (j & 3);
    const int qb = j >> 2;
    const int h = hb & 15, b = hb >> 4;

    // Q A-fragments: A[m=lane&15][k=quad*8+j (+32t)]
    bf16x8 aq[2][2];
#pragma unroll
    for (int sub = 0; sub < 2; ++sub) {
        const int qrow = qb * 128 + w * 32 + sub * 16 + r;
        const size_t qoff = (size_t)(b * SS + qrow) * DD + h * HD;
        aq[sub][0] = *(const bf16x8*)(Q + qoff + quad * 8);
        aq[sub][1] = *(const bf16x8*)(Q + qoff + 32 + quad * 8);
    }

    f32x4 accO[2][4];
#pragma unroll
    for (int sub = 0; sub < 2; ++sub)
#pragma unroll
        for (int nt = 0; nt < 4; ++nt) accO[sub][nt] = f32x4{0.f, 0.f, 0.f, 0.f};
    float lsum[2][4] = {{0.f, 0.f, 0.f, 0.f}, {0.f, 0.f, 0.f, 0.f}};

    // staging addresses (2 rounds each, 256 threads cover 64 rows x 8 chunks)
    const unsigned short* gK[2]; const unsigned short* gV[2]; uint lO[2];
#pragma unroll
    for (int t = 0; t < 2; ++t) {
        int l = t * 256 + tid;
        int c = l ^ ((l >> 3) & 7);
        int row = c >> 3, kc = c & 7;
        int srow = 4 * (row & 15) + (row >> 4);   // sigma: S col nt*16+r <-> kpos 4r+nt
        gK[t] = K + (size_t)(b * SS + srow) * DD + h * HD + kc * 8;
        gV[t] = Vt + (size_t)((b * NH + h) * HD + row) * SS + kc * 8;
        lO[t] = l * 8;
    }
    // LDS frag offsets (ushort units) — same formula serves lsK and lsV
    uint off[2][4];
#pragma unroll
    for (int t = 0; t < 2; ++t)
#pragma unroll
        for (int nt = 0; nt < 4; ++nt) {
            int rowX = nt * 16 + r;
            int c = rowX * 8 + t * 4 + quad;
            off[t][nt] = (uint)((c ^ ((c >> 3) & 7)) * 8);
        }
    // P write/read offsets (row stride 64 shorts, 16B-chunk xor-swizzle by row&7)
    uint pw[4], pr[2];
#pragma unroll
    for (int reg = 0; reg < 4; ++reg) {
        int prow = quad * 4 + reg;
        pw[reg] = (uint)(prow * 64 + ((r >> 1) ^ (prow & 7)) * 8 + (r & 1) * 4);
    }
#pragma unroll
    for (int t = 0; t < 2; ++t)
        pr[t] = (uint)(r * 64 + ((4 * t + quad) ^ (r & 7)) * 8);
    unsigned short* Pw = lsP + w * 4096;   // 2 bufs x 2048

    auto stage = [&](int kb, int vb) {
#pragma unroll
        for (int t = 0; t < 2; ++t) {
            async_cp16(gK[t], &lsK[kb][lO[t]]); gK[t] += 64 * DD;
            async_cp16(gV[t], &lsV[vb][lO[t]]); gV[t] += 64;
        }
    };

    stage(0, 0);
    for (int kt = 0; kt < 32; ++kt) {
        const int cur = kt & 1;
        __syncthreads();   // drains prefetch(kt); fences all prior-tile LDS reads
        if (kt + 1 < 32) stage(cur ^ 1, (kt + 1) % 3);

        // S = Q K^T on tile kt, both subtiles share each K fragment
        f32x4 s[2][4];
#pragma unroll
        for (int sub = 0; sub < 2; ++sub)
#pragma unroll
            for (int nt = 0; nt < 4; ++nt) s[sub][nt] = f32x4{0.f, 0.f, 0.f, 0.f};
#pragma unroll
        for (int t = 0; t < 2; ++t)
#pragma unroll
            for (int nt = 0; nt < 4; ++nt) {
                bf16x8 bk = *(const bf16x8*)&lsK[cur][off[t][nt]];
                s[0][nt] = mfma16(aq[0][t], bk, s[0][nt]);
                s[1][nt] = mfma16(aq[1][t], bk, s[1][nt]);
            }

        // PV of PREVIOUS tile (P in pbuf cur^1, V in lsV[(kt-1)%3]) — hides QK latency
        if (kt > 0) {
            const unsigned short* Pp = Pw + (cur ^ 1) * 2048;
            const unsigned short* Vp = lsV[(kt + 2) % 3];   // (kt-1)%3
#pragma unroll
            for (int t = 0; t < 2; ++t) {
                bf16x8 ap0 = *(const bf16x8*)&Pp[pr[t]];
                bf16x8 ap1 = *(const bf16x8*)&Pp[1024 + pr[t]];
#pragma unroll
                for (int nt = 0; nt < 4; ++nt) {
                    bf16x8 bv = *(const bf16x8*)&Vp[off[t][nt]];
                    accO[0][nt] = mfma16(ap0, bv, accO[0][nt]);
                    accO[1][nt] = mfma16(ap1, bv, accO[1][nt]);
                }
            }
        }

        // p = exp2(s); packed P write into pbuf cur (read next iteration)
        unsigned short* Pc = Pw + cur * 2048;
#pragma unroll
        for (int sub = 0; sub < 2; ++sub)
#pragma unroll
            for (int reg = 0; reg < 4; ++reg) {
                float p0 = __builtin_amdgcn_exp2f(s[sub][0][reg]);
                float p1 = __builtin_amdgcn_exp2f(s[sub][1][reg]);
                float p2 = __builtin_amdgcn_exp2f(s[sub][2][reg]);
                float p3 = __builtin_amdgcn_exp2f(s[sub][3][reg]);
                lsum[sub][reg] += (p0 + p1) + (p2 + p3);
                bf16x4 pk = {(__bf16)p0, (__bf16)p1, (__bf16)p2, (__bf16)p3};
                *(bf16x4*)&Pc[sub * 1024 + pw[reg]] = pk;
            }
    }

    // drain: PV of tile 31 (pbuf 1, V[31%3=1])
    {
        const unsigned short* Pp = Pw + 2048;
        const unsigned short* Vp = lsV[1];
#pragma unroll
        for (int t = 0; t < 2; ++t) {
            bf16x8 ap0 = *(const bf16x8*)&Pp[pr[t]];
            bf16x8 ap1 = *(const bf16x8*)&Pp[1024 + pr[t]];
#pragma unroll
            for (int nt = 0; nt < 4; ++nt) {
                bf16x8 bv = *(const bf16x8*)&Vp[off[t][nt]];
                accO[0][nt] = mfma16(ap0, bv, accO[0][nt]);
                accO[1][nt] = mfma16(ap1, bv, accO[1][nt]);
            }
        }
    }

    // epilogue: reduce l across the 16 row-lanes, then O/l -> Ctx bf16
#pragma unroll
    for (int sub = 0; sub < 2; ++sub) {
        float linv[4];
#pragma unroll
        for (int reg = 0; reg < 4; ++reg) {
            float l = lsum[sub][reg];
            l += __shfl_xor(l, 1);
            l += __shfl_xor(l, 2);
            l += __shfl_xor(l, 4);
            l += __shfl_xor(l, 8);
            linv[reg] = 1.0f / l;
        }
#pragma unroll
        for (int nt = 0; nt < 4; ++nt) {
            int d = nt * 16 + r;
#pragma unroll
            for (int reg = 0; reg < 4; ++reg) {
                int qr = qb * 128 + w * 32 + sub * 16 + quad * 4 + reg;
                Ctx[(size_t)(b * SS + qr) * DD + h * HD + d] = f2bf(accO[sub][nt][reg] * linv[reg]);
            }
        }
    }
}

extern "C" void kernel_launch(void* const* d_in, const int* in_sizes, int n_in,
                              void* d_out, int out_size, void* d_ws, size_t ws_size,
                              hipStream_t stream) {
    (void)in_sizes; (void)n_in; (void)out_size; (void)ws_size;
    const float* H  = (const float*)d_in[0];
    const float* Wq = (const float*)d_in[1];
    const float* bq = (const float*)d_in[2];
    const float* Wk = (const float*)d_in[3];
    const float* bk = (const float*)d_in[4];
    const float* Wo = (const float*)d_in[5];
    const float* bo = (const float*)d_in[6];
    float* Out = (float*)d_out;

    char* ws = (char*)d_ws;
    unsigned short* Hb  = (unsigned short*)(ws);                 // 8 MB
    unsigned short* Qb  = (unsigned short*)(ws + 8388608);       // 8 MB (pre-scaled)
    unsigned short* Kb  = (unsigned short*)(ws + 16777216);      // 8 MB
    unsigned short* Ctx = (unsigned short*)(ws + 25165824);      // 8 MB
    unsigned short* Vt  = (unsigned short*)(ws + 33554432);      // 8 MB
    unsigned short* Wqb = (unsigned short*)(ws + 41943040);      // 2 MB
    unsigned short* Wkb = (unsigned short*)(ws + 44040192);      // 2 MB
    unsigned short* Wob = (unsigned short*)(ws + 46137344);      // 2 MB

    k_prep<<<dim3(2048), dim3(256), 0, stream>>>(H, Wq, Wk, Wo, Hb, Vt, Wqb, Wkb, Wob);
    k_gemm_qk<<<dim3(512), dim3(256), 0, stream>>>(Hb, Wqb, Wkb, bq, bk, Qb, Kb);
    k_attn<<<dim3(512), dim3(256), 0, stream>>>(Qb, Kb, Vt, Ctx);
    k_gemm_out<<<dim3(512), dim3(256), 0, stream>>>(Ctx, Wob, bo, Out);
}

// Round 9
// 167.706 us; speedup vs baseline: 1.0540x; 1.0113x over previous
//
#include <hip/hip_runtime.h>
#include <stdint.h>

// Problem dims (fixed)
#define BB 2
#define SS 2048
#define DD 1024
#define NH 16
#define HD 64
#define MM 4096   // BB*SS

typedef __bf16 bf16x8 __attribute__((ext_vector_type(8)));
typedef __bf16 bf16x4 __attribute__((ext_vector_type(4)));
typedef float  f32x4  __attribute__((ext_vector_type(4)));

__device__ __forceinline__ unsigned short f2bf(float f) {
    __bf16 h = (__bf16)f;                       // hw v_cvt, RNE
    return __builtin_bit_cast(unsigned short, h);
}

// async global->LDS, 16B per lane. LDS dst must be wave-uniform base + lane*16.
// R5 lesson: this is also the coalescing transform (global side lane-contiguous).
// R6 lesson: 2-wave blocks = same waves/CU as 4-wave at half grid; keep 256 threads.
// R7 lesson: XCD swizzle cut FETCH 70->12MB but time flat -> attn is chain-latency-bound.
// R8 lesson: PV software-pipelining (P/V multi-buffer) regressed 56->67us — the ~56us
// attn plateau is structural (matches guide m99-m141: pipelining a drain-bound loop is
// neutral/worse). Do not re-attempt source-level pipelining on this structure.
__device__ __forceinline__ void async_cp16(const void* g, const void* l) {
    __builtin_amdgcn_global_load_lds(
        (const __attribute__((address_space(1))) void*)(uintptr_t)g,
        (__attribute__((address_space(3))) void*)(uint32_t)(uintptr_t)l,
        16, 0, 0);
}

__device__ __forceinline__ f32x4 mfma16(bf16x8 a, bf16x8 b, f32x4 c) {
    return __builtin_amdgcn_mfma_f32_16x16x32_bf16(a, b, c, 0, 0, 0);
}

// ---------------- fused prep: H->Hb+Vt (blocks 0..511) and W->bf16 (blocks 512..2047) ----
__global__ __launch_bounds__(256) void k_prep(const float* __restrict__ H,
                                              const float* __restrict__ Wq,
                                              const float* __restrict__ Wk,
                                              const float* __restrict__ Wo,
                                              unsigned short* __restrict__ Hb,
                                              unsigned short* __restrict__ Vt,
                                              unsigned short* __restrict__ Wqb,
                                              unsigned short* __restrict__ Wkb,
                                              unsigned short* __restrict__ Wob) {
    __shared__ float tile[128][68];
    const int bx = blockIdx.x;
    const int t = threadIdx.x;
    if (bx >= 512) {  // weight conversion
        int g = bx - 512;
        const float* src; unsigned short* dst; int base;
        if (g < 512)       { src = Wq; dst = Wqb; base = g; }
        else if (g < 1024) { src = Wk; dst = Wkb; base = g - 512; }
        else               { src = Wo; dst = Wob; base = g - 1024; }
        int i = (base * 256 + t) * 8;
        float4 a = *(const float4*)(src + i);
        float4 b = *(const float4*)(src + i + 4);
        unsigned short o[8];
        o[0] = f2bf(a.x); o[1] = f2bf(a.y); o[2] = f2bf(a.z); o[3] = f2bf(a.w);
        o[4] = f2bf(b.x); o[5] = f2bf(b.y); o[6] = f2bf(b.z); o[7] = f2bf(b.w);
        *(ulonglong2*)(dst + i) = *(ulonglong2*)o;
        return;
    }
    const int sb = bx & 15, h = (bx >> 4) & 15, b = bx >> 8;
    const int col4 = t & 15;
    const int srow0 = t >> 4;
#pragma unroll
    for (int p = 0; p < 8; ++p) {
        int s = p * 16 + srow0;
        float4 v = *(const float4*)(H + (size_t)(b * SS + sb * 128 + s) * DD + h * HD + col4 * 4);
        *(float4*)&tile[s][col4 * 4] = v;
    }
    __syncthreads();
#pragma unroll
    for (int it = 0; it < 4; ++it) {
        int task = it * 256 + t;
        int s = task >> 3;
        int dg = task & 7;
        unsigned short pk[8];
#pragma unroll
        for (int j = 0; j < 8; ++j) pk[j] = f2bf(tile[s][dg * 8 + j]);
        *(ulonglong2*)(Hb + (size_t)(b * SS + sb * 128 + s) * DD + h * HD + dg * 8) = *(ulonglong2*)pk;
    }
#pragma unroll
    for (int it = 0; it < 4; ++it) {
        int task = it * 256 + t;
        int d = task >> 4;
        int sg = task & 15;
        unsigned short pk[8];
#pragma unroll
        for (int j = 0; j < 8; ++j) pk[j] = f2bf(tile[sg * 8 + j][d]);
        *(ulonglong2*)(Vt + (size_t)((b * NH + h) * HD + d) * SS + sb * 128 + sg * 8) = *(ulonglong2*)pk;
    }
}

// ---------------- TM x 128 MFMA GEMM, BK=64, double-buffered, 1 barrier/iter ----------------
template <int TM, bool BF16OUT>
__device__ __forceinline__ void gemm_body(const unsigned short* __restrict__ A,
                                          const unsigned short* __restrict__ Bt,
                                          const float* __restrict__ bias,
                                          void* __restrict__ Cp, float oscale,
                                          int mBase, int nBase) {
    constexpr int MT = TM / 32;
    constexpr int AR = TM / 32;
    __shared__ unsigned short lsA[2][TM * 64];
    __shared__ unsigned short lsB[2][128 * 64];
    const int tid = threadIdx.x;
    const int lane = tid & 63;
    const int w = tid >> 6;
    const int wm = w & 1, wn = w >> 1;
    const int r = lane & 15, quad = lane >> 4;

    const unsigned short* gA[AR]; uint laOff[AR];
#pragma unroll
    for (int t = 0; t < AR; ++t) {
        int l = t * 256 + tid;
        int c = l ^ ((l >> 3) & 7);
        int row = c >> 3, kc = c & 7;
        gA[t] = A + (size_t)(mBase + row) * 1024 + kc * 8;
        laOff[t] = l * 8;
    }
    const unsigned short* gB[4]; uint lbOff[4];
#pragma unroll
    for (int t = 0; t < 4; ++t) {
        int l = t * 256 + tid;
        int c = l ^ ((l >> 3) & 7);
        int row = c >> 3, kc = c & 7;
        gB[t] = Bt + (size_t)(nBase + row) * 1024 + kc * 8;
        lbOff[t] = l * 8;
    }
    uint aOff[2][MT], bOff[2][4];
#pragma unroll
    for (int hh = 0; hh < 2; ++hh) {
#pragma unroll
        for (int mt = 0; mt < MT; ++mt) {
            int rowA = wm * (TM / 2) + mt * 16 + r;
            int c = rowA * 8 + hh * 4 + quad;
            aOff[hh][mt] = (uint)((c ^ ((c >> 3) & 7)) * 8);
        }
#pragma unroll
        for (int nt = 0; nt < 4; ++nt) {
            int rowB = wn * 64 + nt * 16 + r;
            int c = rowB * 8 + hh * 4 + quad;
            bOff[hh][nt] = (uint)((c ^ ((c >> 3) & 7)) * 8);
        }
    }

    f32x4 acc[MT][4];
#pragma unroll
    for (int i = 0; i < MT; ++i)
#pragma unroll
        for (int j = 0; j < 4; ++j) acc[i][j] = f32x4{0.f, 0.f, 0.f, 0.f};

    auto stage = [&](int buf) {
#pragma unroll
        for (int t = 0; t < AR; ++t) { async_cp16(gA[t], &lsA[buf][laOff[t]]); gA[t] += 64; }
#pragma unroll
        for (int t = 0; t < 4; ++t)  { async_cp16(gB[t], &lsB[buf][lbOff[t]]); gB[t] += 64; }
    };

    stage(0);
    for (int kb = 0; kb < 16; ++kb) {
        const int cur = kb & 1;
        __syncthreads();
        if (kb + 1 < 16) stage(cur ^ 1);

#pragma unroll
        for (int hh = 0; hh < 2; ++hh) {
            bf16x8 af[MT], bf[4];
#pragma unroll
            for (int mt = 0; mt < MT; ++mt) af[mt] = *(const bf16x8*)&lsA[cur][aOff[hh][mt]];
#pragma unroll
            for (int nt = 0; nt < 4; ++nt)  bf[nt] = *(const bf16x8*)&lsB[cur][bOff[hh][nt]];
#pragma unroll
            for (int mt = 0; mt < MT; ++mt)
#pragma unroll
                for (int nt = 0; nt < 4; ++nt)
                    acc[mt][nt] = mfma16(af[mt], bf[nt], acc[mt][nt]);
        }
    }

    float bv[4];
#pragma unroll
    for (int nt = 0; nt < 4; ++nt) bv[nt] = bias[nBase + wn * 64 + nt * 16 + r];
#pragma unroll
    for (int mt = 0; mt < MT; ++mt)
#pragma unroll
        for (int nt = 0; nt < 4; ++nt) {
            int colg = nBase + wn * 64 + nt * 16 + r;
#pragma unroll
            for (int reg = 0; reg < 4; ++reg) {
                int rowg = mBase + wm * (TM / 2) + mt * 16 + quad * 4 + reg;
                float v = (acc[mt][nt][reg] + bv[nt]) * oscale;
                if (BF16OUT)
                    ((unsigned short*)Cp)[(size_t)rowg * 1024 + colg] = f2bf(v);
                else
                    ((float*)Cp)[(size_t)rowg * 1024 + colg] = v;
            }
        }
}

#define QSCALE 0.1803368801111137f   // (1/sqrt(64)) * log2(e)

// 512 blocks, id = x*64 + y' so all 8 n-blocks of one A-strip share id%8 -> one XCD L2.
__global__ __launch_bounds__(256) void k_gemm_qk(const unsigned short* __restrict__ Hb,
                                                 const unsigned short* __restrict__ Wqb,
                                                 const unsigned short* __restrict__ Wkb,
                                                 const float* __restrict__ bq,
                                                 const float* __restrict__ bk,
                                                 unsigned short* __restrict__ Q,
                                                 unsigned short* __restrict__ K) {
    const int id = blockIdx.x;
    const int x = id >> 6, yp = id & 63;
    const int z = yp >> 5, y = yp & 31;
    const unsigned short* Bt = z ? Wkb : Wqb;
    const float* bias = z ? bk : bq;
    unsigned short* C = z ? K : Q;
    float os = z ? 1.0f : QSCALE;
    gemm_body<128, true>(Hb, Bt, bias, C, os, y * 128, x * 128);
}

__global__ __launch_bounds__(256) void k_gemm_out(const unsigned short* __restrict__ Ctx,
                                                  const unsigned short* __restrict__ Wob,
                                                  const float* __restrict__ bo,
                                                  float* __restrict__ Out) {
    const int id = blockIdx.x;
    const int x = id >> 6, y = id & 63;
    gemm_body<64, false>(Ctx, Wob, bo, Out, 1.0f, y * 64, x * 128);
}

// ---------------- flash attention: KT=128 k-tiles (16 barriers), XCD-swizzled grid ----------
// 512 blocks x 256 threads; wave owns 32 q-rows (2 subtiles sharing K/V frags).
// LDS 80KB = 2 blocks/CU (grid-limited anyway). Per iter: stage 128 kpos of K+V,
// one barrier, two 64-k compute halves. Blocks sharing a head's K/V map to one XCD
// (id&7 constant per (h,b)) for L2 locality. Q pre-scaled by scale*log2e.
// This exact structure measured 56.4us (R7) — best of 5 attn variants; keep.
__global__ __launch_bounds__(256) void k_attn(const unsigned short* __restrict__ Q,
                                              const unsigned short* __restrict__ K,
                                              const unsigned short* __restrict__ Vt,
                                              unsigned short* __restrict__ Ctx) {
    __shared__ unsigned short lsK[2][128 * 64];  // [buf][half*64 + sigma-row][d]
    __shared__ unsigned short lsV[2][128 * 64];  // [buf][half*64*64 + d*64 + kpos]
    __shared__ unsigned short lsP[4 * 2048];     // per-wave [q32][k64]
    const int tid = threadIdx.x;
    const int lane = tid & 63;
    const int w = tid >> 6;
    const int r = lane & 15, quad = lane >> 4;
    // XCD swizzle: all 16 q-blocks of one (h,b) share id&7 -> same XCD L2
    const int id = blockIdx.x;
    const int xcd = id & 7, j = id >> 3;
    const int hb = xcd + 8 * (j & 3);
    const int qb = j >> 2;
    const int h = hb & 15, b = hb >> 4;

    // Q A-fragments: A[m=lane&15][k=quad*8+j (+32t)]
    bf16x8 aq[2][2];
#pragma unroll
    for (int sub = 0; sub < 2; ++sub) {
        const int qrow = qb * 128 + w * 32 + sub * 16 + r;
        const size_t qoff = (size_t)(b * SS + qrow) * DD + h * HD;
        aq[sub][0] = *(const bf16x8*)(Q + qoff + quad * 8);
        aq[sub][1] = *(const bf16x8*)(Q + qoff + 32 + quad * 8);
    }

    f32x4 accO[2][4];
#pragma unroll
    for (int sub = 0; sub < 2; ++sub)
#pragma unroll
        for (int nt = 0; nt < 4; ++nt) accO[sub][nt] = f32x4{0.f, 0.f, 0.f, 0.f};
    float lsum[2][4] = {{0.f, 0.f, 0.f, 0.f}, {0.f, 0.f, 0.f, 0.f}};

    // staging addresses: 4 rounds K + 4 rounds V cover 128 rows x 8 chunks each.
    const unsigned short* gK[4]; const unsigned short* gV[4]; uint lO[4];
#pragma unroll
    for (int t = 0; t < 4; ++t) {
        int l = t * 256 + tid;
        int c = l ^ ((l >> 3) & 7);
        int half = c >> 9, kc = c & 7;
        int rr = (c >> 3) & 63;
        int srow = half * 64 + 4 * (rr & 15) + (rr >> 4);   // sigma within 64-half
        gK[t] = K + (size_t)(b * SS + srow) * DD + h * HD + kc * 8;
        gV[t] = Vt + (size_t)((b * NH + h) * HD + rr) * SS + half * 64 + kc * 8;
        lO[t] = l * 8;
    }
    // LDS frag offsets within a 64-half (add half*4096 shorts; swizzle commutes)
    uint off[2][4];
#pragma unroll
    for (int t = 0; t < 2; ++t)
#pragma unroll
        for (int nt = 0; nt < 4; ++nt) {
            int rowX = nt * 16 + r;
            int c = rowX * 8 + t * 4 + quad;
            off[t][nt] = (uint)((c ^ ((c >> 3) & 7)) * 8);
        }
    // P write/read offsets (row stride 64 shorts, 16B-chunk xor-swizzle by row&7)
    uint pw[4], pr[2];
#pragma unroll
    for (int reg = 0; reg < 4; ++reg) {
        int prow = quad * 4 + reg;
        pw[reg] = (uint)(prow * 64 + ((r >> 1) ^ (prow & 7)) * 8 + (r & 1) * 4);
    }
#pragma unroll
    for (int t = 0; t < 2; ++t)
        pr[t] = (uint)(r * 64 + ((4 * t + quad) ^ (r & 7)) * 8);
    unsigned short* Pw = lsP + w * 2048;

    auto stage = [&](int buf) {
#pragma unroll
        for (int t = 0; t < 4; ++t) {
            async_cp16(gK[t], &lsK[buf][lO[t]]); gK[t] += 128 * DD;
            async_cp16(gV[t], &lsV[buf][lO[t]]); gV[t] += 128;
        }
    };

    stage(0);
    for (int kt = 0; kt < 16; ++kt) {
        const int cur = kt & 1;
        __syncthreads();   // drains vmcnt: buf[cur] ready, prev reads of buf[cur^1] done
        if (kt + 1 < 16) stage(cur ^ 1);

#pragma unroll
        for (int half = 0; half < 2; ++half) {
            const uint ho = (uint)half * 4096;

            // S = Q K^T, both subtiles share each K fragment
            f32x4 s[2][4];
#pragma unroll
            for (int sub = 0; sub < 2; ++sub)
#pragma unroll
                for (int nt = 0; nt < 4; ++nt) s[sub][nt] = f32x4{0.f, 0.f, 0.f, 0.f};
#pragma unroll
            for (int t = 0; t < 2; ++t)
#pragma unroll
                for (int nt = 0; nt < 4; ++nt) {
                    bf16x8 bk = *(const bf16x8*)&lsK[cur][ho + off[t][nt]];
                    s[0][nt] = mfma16(aq[0][t], bk, s[0][nt]);
                    s[1][nt] = mfma16(aq[1][t], bk, s[1][nt]);
                }

            // p = exp2(s); packed P write (cols = actual kpos 4r+nt within half)
#pragma unroll
            for (int sub = 0; sub < 2; ++sub)
#pragma unroll
                for (int reg = 0; reg < 4; ++reg) {
                    float p0 = __builtin_amdgcn_exp2f(s[sub][0][reg]);
                    float p1 = __builtin_amdgcn_exp2f(s[sub][1][reg]);
                    float p2 = __builtin_amdgcn_exp2f(s[sub][2][reg]);
                    float p3 = __builtin_amdgcn_exp2f(s[sub][3][reg]);
                    lsum[sub][reg] += (p0 + p1) + (p2 + p3);
                    bf16x4 pk = {(__bf16)p0, (__bf16)p1, (__bf16)p2, (__bf16)p3};
                    *(bf16x4*)&Pw[sub * 1024 + pw[reg]] = pk;
                }
            // no barrier: P is per-wave, same-wave DS ops are ordered

            // O += P V, both subtiles share each V fragment
#pragma unroll
            for (int t = 0; t < 2; ++t) {
                bf16x8 ap0 = *(const bf16x8*)&Pw[pr[t]];
                bf16x8 ap1 = *(const bf16x8*)&Pw[1024 + pr[t]];
#pragma unroll
                for (int nt = 0; nt < 4; ++nt) {
                    bf16x8 bv = *(const bf16x8*)&lsV[cur][ho + off[t][nt]];
                    accO[0][nt] = mfma16(ap0, bv, accO[0][nt]);
                    accO[1][nt] = mfma16(ap1, bv, accO[1][nt]);
                }
            }
        }
    }

    // epilogue: reduce l across the 16 row-lanes, then O/l -> Ctx bf16
#pragma unroll
    for (int sub = 0; sub < 2; ++sub) {
        float linv[4];
#pragma unroll
        for (int reg = 0; reg < 4; ++reg) {
            float l = lsum[sub][reg];
            l += __shfl_xor(l, 1);
            l += __shfl_xor(l, 2);
            l += __shfl_xor(l, 4);
            l += __shfl_xor(l, 8);
            linv[reg] = 1.0f / l;
        }
#pragma unroll
        for (int nt = 0; nt < 4; ++nt) {
            int d = nt * 16 + r;
#pragma unroll
            for (int reg = 0; reg < 4; ++reg) {
                int qr = qb * 128 + w * 32 + sub * 16 + quad * 4 + reg;
                Ctx[(size_t)(b * SS + qr) * DD + h * HD + d] = f2bf(accO[sub][nt][reg] * linv[reg]);
            }
        }
    }
}

extern "C" void kernel_launch(void* const* d_in, const int* in_sizes, int n_in,
                              void* d_out, int out_size, void* d_ws, size_t ws_size,
                              hipStream_t stream) {
    (void)in_sizes; (void)n_in; (void)out_size; (void)ws_size;
    const float* H  = (const float*)d_in[0];
    const float* Wq = (const float*)d_in[1];
    const float* bq = (const float*)d_in[2];
    const float* Wk = (const float*)d_in[3];
    const float* bk = (const float*)d_in[4];
    const float* Wo = (const float*)d_in[5];
    const float* bo = (const float*)d_in[6];
    float* Out = (float*)d_out;

    char* ws = (char*)d_ws;
    unsigned short* Hb  = (unsigned short*)(ws);                 // 8 MB
    unsigned short* Qb  = (unsigned short*)(ws + 8388608);       // 8 MB (pre-scaled)
    unsigned short* Kb  = (unsigned short*)(ws + 16777216);      // 8 MB
    unsigned short* Ctx = (unsigned short*)(ws + 25165824);      // 8 MB
    unsigned short* Vt  = (unsigned short*)(ws + 33554432);      // 8 MB
    unsigned short* Wqb = (unsigned short*)(ws + 41943040);      // 2 MB
    unsigned short* Wkb = (unsigned short*)(ws + 44040192);      // 2 MB
    unsigned short* Wob = (unsigned short*)(ws + 46137344);      // 2 MB

    k_prep<<<dim3(2048), dim3(256), 0, stream>>>(H, Wq, Wk, Wo, Hb, Vt, Wqb, Wkb, Wob);
    k_gemm_qk<<<dim3(512), dim3(256), 0, stream>>>(Hb, Wqb, Wkb, bq, bk, Qb, Kb);
    k_attn<<<dim3(512), dim3(256), 0, stream>>>(Qb, Kb, Vt, Ctx);
    k_gemm_out<<<dim3(512), dim3(256), 0, stream>>>(Ctx, Wob, bo, Out);
}